// Round 3
// baseline (54773.126 us; speedup 1.0000x reference)
//
#include <hip/hip_runtime.h>

typedef unsigned short u16;
typedef unsigned int   u32;
typedef unsigned long long u64;

#define LTC_B 32
#define LTC_L 1024
#define LTC_D 512
#define LTC_H 512
#define GP 16              // workgroups per group (weight slices)
#define GB 16              // batches per group

typedef _Float16 f16x8  __attribute__((ext_vector_type(8)));
typedef _Float16 f16x2t __attribute__((ext_vector_type(2)));
typedef float    f32x4  __attribute__((ext_vector_type(4)));

static __device__ __forceinline__ u32 packh(float a, float b) {
    f16x2t p; p[0] = (_Float16)a; p[1] = (_Float16)b;
    return __builtin_bit_cast(u32, p);
}
static __device__ __forceinline__ float unplo(u32 w) {
    return (float)__builtin_bit_cast(f16x2t, w)[0];
}
static __device__ __forceinline__ float unphi(u32 w) {
    return (float)__builtin_bit_cast(f16x2t, w)[1];
}
static __device__ __forceinline__ float sigm(float x) {
    return 1.f / (1.f + __expf(-x));
}
static __device__ __forceinline__ float tanh_f(float x) {
    float e = __expf(2.f * x);          // inf-safe: e=inf -> 1, e=0 -> -1
    return 1.f - 2.f / (e + 1.f);
}
static __device__ __forceinline__ f16x8 cvt8(const float* p) {
    const float4 a = *(const float4*)p;
    const float4 b = *(const float4*)(p + 4);
    f16x8 r;
    r[0] = (_Float16)a.x; r[1] = (_Float16)a.y; r[2] = (_Float16)a.z; r[3] = (_Float16)a.w;
    r[4] = (_Float16)b.x; r[5] = (_Float16)b.y; r[6] = (_Float16)b.z; r[7] = (_Float16)b.w;
    return r;
}

// ---------------------------------------------------------------------------
// C[M,512](f16) = A[M,512](f32) . W[:,:512]^T(f32, row stride ldb) + bias(f32)
// 64x64 tile per wave, 4x4 MFMA 16x16x32 f16, direct-from-global fragments.
// ---------------------------------------------------------------------------
__global__ __launch_bounds__(256) void gemm_a32_c16(
    const float* __restrict__ A, const float* __restrict__ W, int ldb,
    const float* __restrict__ bias, u16* __restrict__ C)
{
    const int wave = threadIdx.x >> 6;
    const int lane = threadIdx.x & 63;
    const int tile = blockIdx.x * 4 + wave;
    const int nt = tile & 7;
    const int mt = tile >> 3;
    const int r16 = lane & 15;
    const int kq  = (lane >> 4) * 8;

    const float* ap = A + (size_t)(mt * 64 + r16) * LTC_D + kq;
    const float* wp = W + (size_t)(nt * 64 + r16) * ldb + kq;

    f32x4 acc[4][4];
    #pragma unroll
    for (int i = 0; i < 4; ++i)
        #pragma unroll
        for (int jj = 0; jj < 4; ++jj) acc[i][jj] = (f32x4){0.f, 0.f, 0.f, 0.f};

    for (int ks = 0; ks < 16; ++ks) {
        f16x8 af[4], bf[4];
        #pragma unroll
        for (int t = 0; t < 4; ++t) {
            af[t] = cvt8(ap + (size_t)t * 16 * LTC_D + ks * 32);
            bf[t] = cvt8(wp + (size_t)t * 16 * ldb  + ks * 32);
        }
        #pragma unroll
        for (int mi = 0; mi < 4; ++mi)
            #pragma unroll
            for (int ni = 0; ni < 4; ++ni)
                acc[mi][ni] = __builtin_amdgcn_mfma_f32_16x16x32_f16(
                    af[mi], bf[ni], acc[mi][ni], 0, 0, 0);
    }
    const int row = (lane >> 4) * 4;   // C/D: col=lane&15, row=(lane>>4)*4+reg
    const int col = lane & 15;
    #pragma unroll
    for (int ni = 0; ni < 4; ++ni) {
        const int n = nt * 64 + ni * 16 + col;
        const float bv = bias[n];
        #pragma unroll
        for (int mi = 0; mi < 4; ++mi)
            #pragma unroll
            for (int r = 0; r < 4; ++r) {
                _Float16 h = (_Float16)(acc[mi][ni][r] + bv);
                C[(size_t)(mt * 64 + mi * 16 + row + r) * LTC_H + n] =
                    __builtin_bit_cast(u16, h);
            }
    }
}

// ---------------------------------------------------------------------------
// C[M,512](f32) = A[M,512](f16) . W^T(f32, row stride 512) + bias(f32)
// ---------------------------------------------------------------------------
__global__ __launch_bounds__(256) void gemm_a16_c32(
    const u16* __restrict__ A, const float* __restrict__ W,
    const float* __restrict__ bias, float* __restrict__ C)
{
    const int wave = threadIdx.x >> 6;
    const int lane = threadIdx.x & 63;
    const int tile = blockIdx.x * 4 + wave;
    const int nt = tile & 7;
    const int mt = tile >> 3;
    const int r16 = lane & 15;
    const int kq  = (lane >> 4) * 8;

    const _Float16* ap = (const _Float16*)A + (size_t)(mt * 64 + r16) * LTC_D + kq;
    const float*    wp = W + (size_t)(nt * 64 + r16) * LTC_H + kq;

    f32x4 acc[4][4];
    #pragma unroll
    for (int i = 0; i < 4; ++i)
        #pragma unroll
        for (int jj = 0; jj < 4; ++jj) acc[i][jj] = (f32x4){0.f, 0.f, 0.f, 0.f};

    for (int ks = 0; ks < 16; ++ks) {
        f16x8 af[4], bf[4];
        #pragma unroll
        for (int t = 0; t < 4; ++t) {
            af[t] = *(const f16x8*)(ap + (size_t)t * 16 * LTC_D + ks * 32);
            bf[t] = cvt8(wp + (size_t)t * 16 * LTC_H + ks * 32);
        }
        #pragma unroll
        for (int mi = 0; mi < 4; ++mi)
            #pragma unroll
            for (int ni = 0; ni < 4; ++ni)
                acc[mi][ni] = __builtin_amdgcn_mfma_f32_16x16x32_f16(
                    af[mi], bf[ni], acc[mi][ni], 0, 0, 0);
    }
    const int row = (lane >> 4) * 4;
    const int col = lane & 15;
    #pragma unroll
    for (int ni = 0; ni < 4; ++ni) {
        const int n = nt * 64 + ni * 16 + col;
        const float bv = bias[n];
        #pragma unroll
        for (int mi = 0; mi < 4; ++mi)
            #pragma unroll
            for (int r = 0; r < 4; ++r)
                C[(size_t)(mt * 64 + mi * 16 + row + r) * LTC_H + n] =
                    acc[mi][ni][r] + bv;
    }
}

// ---------------------------------------------------------------------------
// Sequential ODE scan. 2 groups x 16 batches; each group = 16 WGs, WG wp owns
// W_rec rows [32wp,32wp+32) and Wg_h rows [32wp,32wp+32) resident in LDS (f16).
// Cross-WG exchange: FENCE-FREE stamped publication. Each thread publishes its
// h pair packed with the sub-step counter into one aligned u64 via a RELAXED
// agent-scope atomic store (plain UC store at the LLC, no L2 maintenance ops —
// acquire/release at agent scope would emit buffer_inv/wbl2 and thrash L2,
// which is what made round 2 46 ms). Gatherers poll the stamped words directly:
// seeing stamp==k implies seeing the data (single-copy atomic 8B). Parity
// double-buffer prevents overwrite of gen-k data before all readers leave.
// ---------------------------------------------------------------------------
__global__ __launch_bounds__(256) void ltc_scan(
    u32* __restrict__ drive,            // f16 pairs; rewritten with fwd
    const u32* __restrict__ gatex,      // f16 pairs
    const float* __restrict__ W_rec,
    const float* __restrict__ W_gate,
    const float* __restrict__ log_tau,
    u64* __restrict__ hbuf,             // [2 parity][2 group][16 b][256] u64
    float* __restrict__ hlast)
{
    const int g   = blockIdx.x >> 4;
    const int wp  = blockIdx.x & 15;
    const int tid = threadIdx.x;
    const int lane = tid & 63;
    const int wv   = tid >> 6;                 // n-tile 0..3 (0-1 rec, 2-3 gate)

    __shared__ u32 Wldsu[64][260];             // 64 rows x 512 f16, +pad
    __shared__ u32 hTu[16][260];               // 16 batches x 512 f16, +pad
    __shared__ float red[64][17];              // matvec results [n][b]

    // one-time: weight slice -> LDS (f16). Row r<32: W_rec[32wp+r]; else Wg_h.
    for (int r = 0; r < 64; ++r) {
        const float* src = (r < 32)
            ? (W_rec  + (size_t)(32 * wp + r) * LTC_H + 2 * tid)
            : (W_gate + (size_t)(32 * wp + r - 32) * (LTC_D + LTC_H) + LTC_D + 2 * tid);
        float2 w2 = *(const float2*)src;
        Wldsu[r][tid] = packh(w2.x, w2.y);
    }
    for (int i = tid; i < 16 * 260; i += 256) (&hTu[0][0])[i] = 0;   // h0 = 0
    __syncthreads();

    // per-thread owned h pair: batch b, rows jg0, jg0+1
    const int b   = tid & 15;
    const int jp  = tid >> 4;                  // 0..15
    const int jg0 = 32 * wp + 2 * jp;
    float h0 = 0.f, h1 = 0.f;
    const float stau0 = (1.f / 6.f) * __expf(-log_tau[jg0]);
    const float stau1 = (1.f / 6.f) * __expf(-log_tau[jg0 + 1]);
    const size_t dbase = (size_t)(g * GB + b) * LTC_L * 256 + 16 * wp + jp;

    const int am  = lane & 15;
    const int kq  = (lane >> 4) * 8;
    const _Float16* hrow = (const _Float16*)&hTu[am][0];
    const _Float16* wrow = (const _Float16*)&Wldsu[wv * 16 + am][0];
    const int hbase_g = g * (GB * 256);

    u32 kp1 = 0;                               // global sub-step counter + 1
    for (int l = 0; l < LTC_L; ++l) {
        const u32 dw = drive[dbase + (size_t)l * 256];
        const u32 gw = gatex[dbase + (size_t)l * 256];
        const float d0 = unplo(dw), d1 = unphi(dw);
        const float gx0 = unplo(gw), gx1 = unphi(gw);
        #pragma unroll 1
        for (int s = 0; s < 6; ++s) {
            // ---- matvec: OUT[b][n] for my 64 rows, all 16 batches ----
            f32x4 acc0 = (f32x4){0.f,0.f,0.f,0.f}, acc1 = acc0;
            #pragma unroll
            for (int ks = 0; ks < 16; ks += 2) {
                f16x8 a0 = *(const f16x8*)(hrow + ks * 32 + kq);
                f16x8 b0 = *(const f16x8*)(wrow + ks * 32 + kq);
                f16x8 a1 = *(const f16x8*)(hrow + (ks + 1) * 32 + kq);
                f16x8 b1 = *(const f16x8*)(wrow + (ks + 1) * 32 + kq);
                acc0 = __builtin_amdgcn_mfma_f32_16x16x32_f16(a0, b0, acc0, 0, 0, 0);
                acc1 = __builtin_amdgcn_mfma_f32_16x16x32_f16(a1, b1, acc1, 0, 0, 0);
            }
            {
                const int n  = wv * 16 + (lane & 15);
                const int rb = (lane >> 4) * 4;
                #pragma unroll
                for (int r = 0; r < 4; ++r) red[n][rb + r] = acc0[r] + acc1[r];
            }
            __syncthreads();
            // ---- elementwise update of my 2 h rows ----
            const float rec0 = red[2 * jp][b],     gh0 = red[32 + 2 * jp][b];
            const float rec1 = red[2 * jp + 1][b], gh1 = red[32 + 2 * jp + 1][b];
            h0 += stau0 * (sigm(gx0 + gh0) * tanh_f(d0 + rec0) - h0);
            h1 += stau1 * (sigm(gx1 + gh1) * tanh_f(d1 + rec1) - h1);
            ++kp1;
            const int par = (int)(kp1 & 1u);
            const int hb  = par * (2 * GB * 256) + hbase_g;
            // ---- publish stamped h pair (relaxed, agent scope, no fences) ----
            const u64 pub = ((u64)kp1 << 32) | (u64)packh(h0, h1);
            __hip_atomic_store(&hbuf[hb + b * 256 + 16 * wp + jp], pub,
                               __ATOMIC_RELAXED, __HIP_MEMORY_SCOPE_AGENT);
            // ---- gather h(k+1): poll stamped words, stamp==kp1 => data valid ----
            {
                bool done[16];
                #pragma unroll
                for (int i = 0; i < 16; ++i) done[i] = false;
                int remaining = 16;
                while (remaining) {
                    const int prev = remaining;
                    #pragma unroll
                    for (int i = 0; i < 16; ++i) {
                        if (!done[i]) {
                            u64 v = __hip_atomic_load(&hbuf[hb + i * 256 + tid],
                                                      __ATOMIC_RELAXED,
                                                      __HIP_MEMORY_SCOPE_AGENT);
                            if ((u32)(v >> 32) == kp1) {
                                hTu[i][tid] = (u32)v;
                                done[i] = true;
                                --remaining;
                            }
                        }
                    }
                    if (remaining && remaining == prev)
                        __builtin_amdgcn_s_sleep(1);
                }
            }
            __syncthreads();                   // hTu complete for next matvec
        }
        drive[dbase + (size_t)l * 256] = packh(h0, h1);   // fwd, in-place
    }
    hlast[(size_t)(g * GB + b) * LTC_H + jg0]     = h0;
    hlast[(size_t)(g * GB + b) * LTC_H + jg0 + 1] = h1;
}

// ---------------------------------------------------------------------------
extern "C" void kernel_launch(void* const* d_in, const int* in_sizes, int n_in,
                              void* d_out, int out_size, void* d_ws, size_t ws_size,
                              hipStream_t stream)
{
    const float* x       = (const float*)d_in[0];
    const float* log_tau = (const float*)d_in[1];
    const float* W_in    = (const float*)d_in[2];
    const float* b_in    = (const float*)d_in[3];
    const float* W_rec   = (const float*)d_in[4];
    const float* W_gate  = (const float*)d_in[5];
    const float* b_gate  = (const float*)d_in[6];
    const float* W_out   = (const float*)d_in[7];
    const float* b_out   = (const float*)d_in[8];

    float* out   = (float*)d_out;                       // (32,1024,512) fp32
    float* hlast = out + (size_t)LTC_B * LTC_L * LTC_H; // (32,512) fp32

    u32* ws    = (u32*)d_ws;                   // 64 MB + 128 KB used
    u32* drive = ws;                           // 8388608 u32 (f16 pairs)
    u32* gatex = ws + 8388608;                 // 8388608 u32
    u64* hbuf  = (u64*)(ws + 16777216);        // 16384 u64 (stamped h pairs)

    const int blocks = (LTC_B * LTC_L / 64) * (LTC_H / 64) / 4;   // 1024

    gemm_a32_c16<<<blocks, 256, 0, stream>>>(x, W_in, LTC_D, b_in, (u16*)drive);
    gemm_a32_c16<<<blocks, 256, 0, stream>>>(x, W_gate, LTC_D + LTC_H, b_gate, (u16*)gatex);
    ltc_scan<<<LTC_B, 256, 0, stream>>>(drive, gatex, W_rec, W_gate, log_tau,
                                        hbuf, hlast);
    gemm_a16_c32<<<blocks, 256, 0, stream>>>((const u16*)drive, W_out, b_out, out);
}

// Round 5
// 13314.926 us; speedup vs baseline: 4.1137x; 4.1137x over previous
//
#include <hip/hip_runtime.h>

typedef unsigned short u16;
typedef unsigned int   u32;
typedef unsigned long long u64;

#define LTC_B 32
#define LTC_L 1024
#define LTC_D 512
#define LTC_H 512
#define NG 8               // groups (ideally one per XCD via blockIdx&7)
#define NP 16              // producer WGs per group (each owns 32+32 W rows)
#define NBG 4              // batches per group

typedef _Float16 f16x8  __attribute__((ext_vector_type(8)));
typedef _Float16 f16x2t __attribute__((ext_vector_type(2)));
typedef float    f32x4  __attribute__((ext_vector_type(4)));

static __device__ __forceinline__ u32 packh(float a, float b) {
    f16x2t p; p[0] = (_Float16)a; p[1] = (_Float16)b;
    return __builtin_bit_cast(u32, p);
}
static __device__ __forceinline__ float unplo(u32 w) {
    return (float)__builtin_bit_cast(f16x2t, w)[0];
}
static __device__ __forceinline__ float unphi(u32 w) {
    return (float)__builtin_bit_cast(f16x2t, w)[1];
}
static __device__ __forceinline__ float sigm(float x) {
    return 1.f / (1.f + __expf(-x));
}
static __device__ __forceinline__ float tanh_f(float x) {
    float e = __expf(2.f * x);          // inf-safe: e=inf -> 1, e=0 -> -1
    return 1.f - 2.f / (e + 1.f);
}
static __device__ __forceinline__ f16x8 cvt8(const float* p) {
    const float4 a = *(const float4*)p;
    const float4 b = *(const float4*)(p + 4);
    f16x8 r;
    r[0] = (_Float16)a.x; r[1] = (_Float16)a.y; r[2] = (_Float16)a.z; r[3] = (_Float16)a.w;
    r[4] = (_Float16)b.x; r[5] = (_Float16)b.y; r[6] = (_Float16)b.z; r[7] = (_Float16)b.w;
    return r;
}

// fast sweep: 4 parallel L1-bypass loads (served by the XCD's coherent L2),
// single waitcnt — avoids round-3's 16x serialized-latency poll sweeps.
static __device__ __forceinline__ void ld4_fast(const u64* p,
        u64& v0, u64& v1, u64& v2, u64& v3) {
    asm volatile(
        "global_load_dwordx2 %0, %4, off sc0\n\t"
        "global_load_dwordx2 %1, %5, off sc0\n\t"
        "global_load_dwordx2 %2, %6, off sc0\n\t"
        "global_load_dwordx2 %3, %7, off sc0\n\t"
        "s_waitcnt vmcnt(0)"
        : "=&v"(v0), "=&v"(v1), "=&v"(v2), "=&v"(v3)
        : "v"(p), "v"(p + 256), "v"(p + 512), "v"(p + 768)
        : "memory");
}
static __device__ __forceinline__ bool stamp4(u64 a, u64 b, u64 c, u64 d, u32 k) {
    return ((u32)(a >> 32) == k) & ((u32)(b >> 32) == k) &
           ((u32)(c >> 32) == k) & ((u32)(d >> 32) == k);
}

// ---------------------------------------------------------------------------
// C[M,512](f16) = A[M,512](f32) . W[:,:512]^T(f32, row stride ldb) + bias(f32)
// ---------------------------------------------------------------------------
__global__ __launch_bounds__(256) void gemm_a32_c16(
    const float* __restrict__ A, const float* __restrict__ W, int ldb,
    const float* __restrict__ bias, u16* __restrict__ C)
{
    const int wave = threadIdx.x >> 6;
    const int lane = threadIdx.x & 63;
    const int tile = blockIdx.x * 4 + wave;
    const int nt = tile & 7;
    const int mt = tile >> 3;
    const int r16 = lane & 15;
    const int kq  = (lane >> 4) * 8;

    const float* ap = A + (size_t)(mt * 64 + r16) * LTC_D + kq;
    const float* wp = W + (size_t)(nt * 64 + r16) * ldb + kq;

    f32x4 acc[4][4];
    #pragma unroll
    for (int i = 0; i < 4; ++i)
        #pragma unroll
        for (int jj = 0; jj < 4; ++jj) acc[i][jj] = (f32x4){0.f, 0.f, 0.f, 0.f};

    for (int ks = 0; ks < 16; ++ks) {
        f16x8 af[4], bf[4];
        #pragma unroll
        for (int t = 0; t < 4; ++t) {
            af[t] = cvt8(ap + (size_t)t * 16 * LTC_D + ks * 32);
            bf[t] = cvt8(wp + (size_t)t * 16 * ldb  + ks * 32);
        }
        #pragma unroll
        for (int mi = 0; mi < 4; ++mi)
            #pragma unroll
            for (int ni = 0; ni < 4; ++ni)
                acc[mi][ni] = __builtin_amdgcn_mfma_f32_16x16x32_f16(
                    af[mi], bf[ni], acc[mi][ni], 0, 0, 0);
    }
    const int row = (lane >> 4) * 4;   // C/D: col=lane&15 (n), row=(lane>>4)*4+reg (m)
    const int col = lane & 15;
    #pragma unroll
    for (int ni = 0; ni < 4; ++ni) {
        const int n = nt * 64 + ni * 16 + col;
        const float bv = bias[n];
        #pragma unroll
        for (int mi = 0; mi < 4; ++mi)
            #pragma unroll
            for (int r = 0; r < 4; ++r) {
                _Float16 h = (_Float16)(acc[mi][ni][r] + bv);
                C[(size_t)(mt * 64 + mi * 16 + row + r) * LTC_H + n] =
                    __builtin_bit_cast(u16, h);
            }
    }
}

// ---------------------------------------------------------------------------
// C[M,512](f32) = A[M,512](f16) . W^T(f32, row stride 512) + bias(f32)
// ---------------------------------------------------------------------------
__global__ __launch_bounds__(256) void gemm_a16_c32(
    const u16* __restrict__ A, const float* __restrict__ W,
    const float* __restrict__ bias, float* __restrict__ C)
{
    const int wave = threadIdx.x >> 6;
    const int lane = threadIdx.x & 63;
    const int tile = blockIdx.x * 4 + wave;
    const int nt = tile & 7;
    const int mt = tile >> 3;
    const int r16 = lane & 15;
    const int kq  = (lane >> 4) * 8;

    const _Float16* ap = (const _Float16*)A + (size_t)(mt * 64 + r16) * LTC_D + kq;
    const float*    wp = W + (size_t)(nt * 64 + r16) * LTC_H + kq;

    f32x4 acc[4][4];
    #pragma unroll
    for (int i = 0; i < 4; ++i)
        #pragma unroll
        for (int jj = 0; jj < 4; ++jj) acc[i][jj] = (f32x4){0.f, 0.f, 0.f, 0.f};

    for (int ks = 0; ks < 16; ++ks) {
        f16x8 af[4], bf[4];
        #pragma unroll
        for (int t = 0; t < 4; ++t) {
            af[t] = *(const f16x8*)(ap + (size_t)t * 16 * LTC_D + ks * 32);
            bf[t] = cvt8(wp + (size_t)t * 16 * LTC_H + ks * 32);
        }
        #pragma unroll
        for (int mi = 0; mi < 4; ++mi)
            #pragma unroll
            for (int ni = 0; ni < 4; ++ni)
                acc[mi][ni] = __builtin_amdgcn_mfma_f32_16x16x32_f16(
                    af[mi], bf[ni], acc[mi][ni], 0, 0, 0);
    }
    const int row = (lane >> 4) * 4;
    const int col = lane & 15;
    #pragma unroll
    for (int ni = 0; ni < 4; ++ni) {
        const int n = nt * 64 + ni * 16 + col;
        const float bv = bias[n];
        #pragma unroll
        for (int mi = 0; mi < 4; ++mi)
            #pragma unroll
            for (int r = 0; r < 4; ++r)
                C[(size_t)(mt * 64 + mi * 16 + row + r) * LTC_H + n] =
                    acc[mi][ni][r] + bv;
    }
}

// ---------------------------------------------------------------------------
// ODE scan: 8 groups x 4 batches, 16 producer WGs per group (128 WGs).
// Weights live in registers as MFMA B-fragments. Exchange = stamped u64
// (stamp<<32 | f16 pair): BOTH copies published fire-and-forget BEFORE any
// gathering (deadlock-free under any WG->XCD placement): fast copy = plain
// store into the XCD's L2, safe copy = agent-scope relaxed atomic (LLC).
// Gather: batched fast sweep (sc0, 1 vmcnt) then safe sweep; strictly
// increasing stamps make all stale values benign. Bounded spins: protocol
// failure => wrong answer (absmax signal), never a hang.
// ---------------------------------------------------------------------------
__global__ __launch_bounds__(256) void ltc_scan(
    u32* __restrict__ drive,            // f16 pairs; rewritten with fwd
    const u32* __restrict__ gatex,      // f16 pairs
    const float* __restrict__ W_rec,
    const float* __restrict__ W_gate,
    const float* __restrict__ log_tau,
    u64* __restrict__ hfast,            // [2 par][8 g][4 b][256] stamped pairs
    u64* __restrict__ hsafe,            // LLC mirror, same layout
    float* __restrict__ hlast)
{
    const int g   = blockIdx.x & 7;     // group (-> XCD under round-robin)
    const int p   = blockIdx.x >> 3;    // producer slice 0..15
    const int tid = threadIdx.x;
    const int lane = tid & 63;
    const int wv   = tid >> 6;          // n-tile: 0-1 rec rows, 2-3 gate rows

    __shared__ u32 hTu[16][260];        // h as f16 pairs; rows 0-3 = batches
    __shared__ float red[64][17];       // matvec results [n][m]

    // ---- one-time: B-fragments (my 32 W_rec + 32 Wg_h rows) into registers
    const int nl = wv * 16 + (lane & 15);      // 0..63
    const int kq = (lane >> 4) * 8;
    const float* wrow = (nl < 32)
        ? (W_rec  + (size_t)(32 * p + nl) * LTC_H)
        : (W_gate + (size_t)(32 * p + nl - 32) * (LTC_D + LTC_H) + LTC_D);
    f16x8 Wf[16];
    #pragma unroll
    for (int ks = 0; ks < 16; ++ks) Wf[ks] = cvt8(wrow + ks * 32 + kq);

    for (int i = tid; i < 16 * 260; i += 256) (&hTu[0][0])[i] = 0;  // h0 = 0
    __syncthreads();

    // ---- update-thread setup (wave 0 only: 4 b x 16 pairs = 64 threads)
    const int ub = tid >> 4;            // local batch (tid<64)
    const int jp = tid & 15;
    const int j0 = 32 * p + 2 * jp;
    const int gb = g * NBG + ub;        // global batch
    float h0 = 0.f, h1 = 0.f, stau0 = 0.f, stau1 = 0.f;
    size_t dwofs = 0;
    if (tid < 64) {
        stau0 = (1.f / 6.f) * __expf(-log_tau[j0]);
        stau1 = (1.f / 6.f) * __expf(-log_tau[j0 + 1]);
        dwofs = (size_t)gb * LTC_L * 256 + 16 * p + jp;
    }

    const _Float16* hrow = (const _Float16*)&hTu[lane & 15][0];
    u32 kp1 = 0;

    // prime l=0 inputs
    u32 dw = 0, gw = 0;
    if (tid < 64) { dw = drive[dwofs]; gw = gatex[dwofs]; }

    for (int l = 0; l < LTC_L; ++l) {
        const float d0 = unplo(dw), d1 = unphi(dw);
        const float gx0 = unplo(gw), gx1 = unphi(gw);
        // prefetch next step's inputs (overlaps with 6 sub-steps of work)
        u32 dn = 0, gn = 0;
        if (tid < 64 && l + 1 < LTC_L) {
            dn = drive[dwofs + (size_t)(l + 1) * 256];
            gn = gatex[dwofs + (size_t)(l + 1) * 256];
        }
        #pragma unroll 1
        for (int s = 0; s < 6; ++s) {
            // ---- matvec: red[n][m] = sum_k h[m,k] * Wrow(n)[k]
            f32x4 acc = (f32x4){0.f, 0.f, 0.f, 0.f};
            #pragma unroll
            for (int ks = 0; ks < 16; ++ks) {
                const f16x8 a = *(const f16x8*)(hrow + ks * 32 + kq);
                acc = __builtin_amdgcn_mfma_f32_16x16x32_f16(a, Wf[ks], acc, 0, 0, 0);
            }
            {
                const int n  = wv * 16 + (lane & 15);
                const int rb = (lane >> 4) * 4;
                #pragma unroll
                for (int r = 0; r < 4; ++r) red[n][rb + r] = acc[r];
            }
            __syncthreads();
            ++kp1;
            const size_t pbase = (size_t)((kp1 & 1u) * NG + g) * (NBG * 256);
            // ---- update + DUAL publish, both BEFORE any gathering ----
            if (tid < 64) {
                const float rec0 = red[2 * jp][ub],     gh0 = red[32 + 2 * jp][ub];
                const float rec1 = red[2 * jp + 1][ub], gh1 = red[32 + 2 * jp + 1][ub];
                h0 += stau0 * (sigm(gx0 + gh0) * tanh_f(d0 + rec0) - h0);
                h1 += stau1 * (sigm(gx1 + gh1) * tanh_f(d1 + rec1) - h1);
                const u64 v = ((u64)kp1 << 32) | (u64)packh(h0, h1);
                const size_t w = pbase + (size_t)ub * 256 + 16 * p + jp;
                *(volatile u64*)(hfast + w) = v;                  // XCD L2
                __hip_atomic_store(hsafe + w, v, __ATOMIC_RELAXED,
                                   __HIP_MEMORY_SCOPE_AGENT);     // LLC
            }
            // ---- gather: column tid across 4 batch rows (one producer WG) --
            {
                const u64* fb = hfast + pbase + tid;
                const u64* sb = hsafe + pbase + tid;
                u64 a0 = 0, a1 = 0, a2 = 0, a3 = 0;
                bool ok = false;
                for (int it = 0; it < (1 << 18) && !ok; ++it) {
                    ld4_fast(fb, a0, a1, a2, a3);
                    ok = stamp4(a0, a1, a2, a3, kp1);
                    if (!ok) {
                        a0 = __hip_atomic_load(sb,       __ATOMIC_RELAXED,
                                               __HIP_MEMORY_SCOPE_AGENT);
                        a1 = __hip_atomic_load(sb + 256, __ATOMIC_RELAXED,
                                               __HIP_MEMORY_SCOPE_AGENT);
                        a2 = __hip_atomic_load(sb + 512, __ATOMIC_RELAXED,
                                               __HIP_MEMORY_SCOPE_AGENT);
                        a3 = __hip_atomic_load(sb + 768, __ATOMIC_RELAXED,
                                               __HIP_MEMORY_SCOPE_AGENT);
                        ok = stamp4(a0, a1, a2, a3, kp1);
                        if (!ok) __builtin_amdgcn_s_sleep(1);
                    }
                }
                hTu[0][tid] = (u32)a0; hTu[1][tid] = (u32)a1;
                hTu[2][tid] = (u32)a2; hTu[3][tid] = (u32)a3;
            }
            __syncthreads();
        }
        if (tid < 64) drive[dwofs + (size_t)l * 256] = packh(h0, h1);  // fwd
        dw = dn; gw = gn;
    }
    if (tid < 64) {
        hlast[(size_t)gb * LTC_H + j0]     = h0;
        hlast[(size_t)gb * LTC_H + j0 + 1] = h1;
    }
}

// ---------------------------------------------------------------------------
extern "C" void kernel_launch(void* const* d_in, const int* in_sizes, int n_in,
                              void* d_out, int out_size, void* d_ws, size_t ws_size,
                              hipStream_t stream)
{
    const float* x       = (const float*)d_in[0];
    const float* log_tau = (const float*)d_in[1];
    const float* W_in    = (const float*)d_in[2];
    const float* b_in    = (const float*)d_in[3];
    const float* W_rec   = (const float*)d_in[4];
    const float* W_gate  = (const float*)d_in[5];
    const float* b_gate  = (const float*)d_in[6];
    const float* W_out   = (const float*)d_in[7];
    const float* b_out   = (const float*)d_in[8];

    float* out   = (float*)d_out;                       // (32,1024,512) fp32
    float* hlast = out + (size_t)LTC_B * LTC_L * LTC_H; // (32,512) fp32

    u32* ws    = (u32*)d_ws;                   // 64 MB + 256 KB used
    u32* drive = ws;                           // 8388608 u32 (f16 pairs)
    u32* gatex = ws + 8388608;                 // 8388608 u32
    u64* hfast = (u64*)(ws + 16777216);        // 16384 u64 stamped pairs
    u64* hsafe = hfast + 16384;                // LLC mirror

    const int blocks = (LTC_B * LTC_L / 64) * (LTC_H / 64) / 4;   // 1024

    gemm_a32_c16<<<blocks, 256, 0, stream>>>(x, W_in, LTC_D, b_in, (u16*)drive);
    gemm_a32_c16<<<blocks, 256, 0, stream>>>(x, W_gate, LTC_D + LTC_H, b_gate, (u16*)gatex);
    ltc_scan<<<NG * NP, 256, 0, stream>>>(drive, gatex, W_rec, W_gate, log_tau,
                                          hfast, hsafe, hlast);
    gemm_a16_c32<<<blocks, 256, 0, stream>>>((const u16*)drive, W_out, b_out, out);
}

// Round 7
// 10812.650 us; speedup vs baseline: 5.0657x; 1.2314x over previous
//
#include <hip/hip_runtime.h>

typedef unsigned short u16;
typedef unsigned int   u32;
typedef unsigned long long u64;

#define LTC_B 32
#define LTC_L 1024
#define LTC_D 512
#define LTC_H 512
#define NG 8               // groups
#define NP 16              // producer WGs per group (each owns 32+32 W rows)
#define NBG 4              // batches per group

typedef _Float16 f16x8  __attribute__((ext_vector_type(8)));
typedef _Float16 f16x2t __attribute__((ext_vector_type(2)));
typedef float    f32x4  __attribute__((ext_vector_type(4)));

static __device__ __forceinline__ u32 packh(float a, float b) {
    f16x2t p; p[0] = (_Float16)a; p[1] = (_Float16)b;
    return __builtin_bit_cast(u32, p);
}
static __device__ __forceinline__ float unplo(u32 w) {
    return (float)__builtin_bit_cast(f16x2t, w)[0];
}
static __device__ __forceinline__ float unphi(u32 w) {
    return (float)__builtin_bit_cast(f16x2t, w)[1];
}
static __device__ __forceinline__ float sigm(float x) {
    return 1.f / (1.f + __expf(-x));
}
static __device__ __forceinline__ float tanh_f(float x) {
    float e = __expf(2.f * x);          // inf-safe: e=inf -> 1, e=0 -> -1
    return 1.f - 2.f / (e + 1.f);
}
static __device__ __forceinline__ f16x8 cvt8(const float* p) {
    const float4 a = *(const float4*)p;
    const float4 b = *(const float4*)(p + 4);
    f16x8 r;
    r[0] = (_Float16)a.x; r[1] = (_Float16)a.y; r[2] = (_Float16)a.z; r[3] = (_Float16)a.w;
    r[4] = (_Float16)b.x; r[5] = (_Float16)b.y; r[6] = (_Float16)b.z; r[7] = (_Float16)b.w;
    return r;
}
static __device__ __forceinline__ bool stamp4(u64 a, u64 b, u64 c, u64 d, u32 k) {
    return ((u32)(a >> 32) == k) & ((u32)(b >> 32) == k) &
           ((u32)(c >> 32) == k) & ((u32)(d >> 32) == k);
}

// ---------------------------------------------------------------------------
// C[M,512](f16) = A[M,512](f32) . W[:,:512]^T(f32, row stride ldb) + bias(f32)
// ---------------------------------------------------------------------------
__global__ __launch_bounds__(256) void gemm_a32_c16(
    const float* __restrict__ A, const float* __restrict__ W, int ldb,
    const float* __restrict__ bias, u16* __restrict__ C)
{
    const int wave = threadIdx.x >> 6;
    const int lane = threadIdx.x & 63;
    const int tile = blockIdx.x * 4 + wave;
    const int nt = tile & 7;
    const int mt = tile >> 3;
    const int r16 = lane & 15;
    const int kq  = (lane >> 4) * 8;

    const float* ap = A + (size_t)(mt * 64 + r16) * LTC_D + kq;
    const float* wp = W + (size_t)(nt * 64 + r16) * ldb + kq;

    f32x4 acc[4][4];
    #pragma unroll
    for (int i = 0; i < 4; ++i)
        #pragma unroll
        for (int jj = 0; jj < 4; ++jj) acc[i][jj] = (f32x4){0.f, 0.f, 0.f, 0.f};

    for (int ks = 0; ks < 16; ++ks) {
        f16x8 af[4], bf[4];
        #pragma unroll
        for (int t = 0; t < 4; ++t) {
            af[t] = cvt8(ap + (size_t)t * 16 * LTC_D + ks * 32);
            bf[t] = cvt8(wp + (size_t)t * 16 * ldb  + ks * 32);
        }
        #pragma unroll
        for (int mi = 0; mi < 4; ++mi)
            #pragma unroll
            for (int ni = 0; ni < 4; ++ni)
                acc[mi][ni] = __builtin_amdgcn_mfma_f32_16x16x32_f16(
                    af[mi], bf[ni], acc[mi][ni], 0, 0, 0);
    }
    const int row = (lane >> 4) * 4;   // C/D: col=lane&15 (n), row=(lane>>4)*4+reg (m)
    const int col = lane & 15;
    #pragma unroll
    for (int ni = 0; ni < 4; ++ni) {
        const int n = nt * 64 + ni * 16 + col;
        const float bv = bias[n];
        #pragma unroll
        for (int mi = 0; mi < 4; ++mi)
            #pragma unroll
            for (int r = 0; r < 4; ++r) {
                _Float16 h = (_Float16)(acc[mi][ni][r] + bv);
                C[(size_t)(mt * 64 + mi * 16 + row + r) * LTC_H + n] =
                    __builtin_bit_cast(u16, h);
            }
    }
}

// ---------------------------------------------------------------------------
// C[M,512](f32) = A[M,512](f16) . W^T(f32, row stride 512) + bias(f32)
// ---------------------------------------------------------------------------
__global__ __launch_bounds__(256) void gemm_a16_c32(
    const u16* __restrict__ A, const float* __restrict__ W,
    const float* __restrict__ bias, float* __restrict__ C)
{
    const int wave = threadIdx.x >> 6;
    const int lane = threadIdx.x & 63;
    const int tile = blockIdx.x * 4 + wave;
    const int nt = tile & 7;
    const int mt = tile >> 3;
    const int r16 = lane & 15;
    const int kq  = (lane >> 4) * 8;

    const _Float16* ap = (const _Float16*)A + (size_t)(mt * 64 + r16) * LTC_D + kq;
    const float*    wp = W + (size_t)(nt * 64 + r16) * LTC_H + kq;

    f32x4 acc[4][4];
    #pragma unroll
    for (int i = 0; i < 4; ++i)
        #pragma unroll
        for (int jj = 0; jj < 4; ++jj) acc[i][jj] = (f32x4){0.f, 0.f, 0.f, 0.f};

    for (int ks = 0; ks < 16; ++ks) {
        f16x8 af[4], bf[4];
        #pragma unroll
        for (int t = 0; t < 4; ++t) {
            af[t] = *(const f16x8*)(ap + (size_t)t * 16 * LTC_D + ks * 32);
            bf[t] = cvt8(wp + (size_t)t * 16 * LTC_H + ks * 32);
        }
        #pragma unroll
        for (int mi = 0; mi < 4; ++mi)
            #pragma unroll
            for (int ni = 0; ni < 4; ++ni)
                acc[mi][ni] = __builtin_amdgcn_mfma_f32_16x16x32_f16(
                    af[mi], bf[ni], acc[mi][ni], 0, 0, 0);
    }
    const int row = (lane >> 4) * 4;
    const int col = lane & 15;
    #pragma unroll
    for (int ni = 0; ni < 4; ++ni) {
        const int n = nt * 64 + ni * 16 + col;
        const float bv = bias[n];
        #pragma unroll
        for (int mi = 0; mi < 4; ++mi)
            #pragma unroll
            for (int r = 0; r < 4; ++r)
                C[(size_t)(mt * 64 + mi * 16 + row + r) * LTC_H + n] =
                    acc[mi][ni][r] + bv;
    }
}

// ---------------------------------------------------------------------------
// ODE scan: 8 groups x 4 batches, 16 producer WGs per group (128 WGs).
// Exchange = the VALIDATED LLC channel only (rounds 2/3/5 all propagated
// through agent-scope relaxed atomics): stamped u64 (stamp<<32 | f16 pair),
// single sc1 publish, batched 4-load LLC poll sweep, no sleep. The round-6
// XCD-L2 fast path is removed — it failed on HW (stale reads -> budget
// exhaustion). Parity double-buffer bounds producer/consumer skew to 1
// sub-step (publish(k) implies all WGs finished gather(k-2), so parity slot
// k-2 is dead before overwrite). Bounded spins: protocol failure => wrong
// answer (absmax signal), never a hang.
// ---------------------------------------------------------------------------
__global__ __launch_bounds__(256) void ltc_scan(
    u32* __restrict__ drive,            // f16 pairs; rewritten with fwd
    const u32* __restrict__ gatex,      // f16 pairs
    const float* __restrict__ W_rec,
    const float* __restrict__ W_gate,
    const float* __restrict__ log_tau,
    u64* __restrict__ hbuf,             // [2 par][8 g][4 b][256] stamped pairs
    float* __restrict__ hlast)
{
    const int g   = blockIdx.x & 7;     // group
    const int p   = blockIdx.x >> 3;    // producer slice 0..15
    const int tid = threadIdx.x;
    const int lane = tid & 63;
    const int wv   = tid >> 6;          // n-tile: 0-1 rec rows, 2-3 gate rows

    __shared__ u32 hTu[16][260];        // h as f16 pairs; rows 0-3 = batches
    __shared__ float red[64][17];       // matvec results [n][m]

    // ---- one-time: B-fragments (my 32 W_rec + 32 Wg_h rows) into registers
    const int nl = wv * 16 + (lane & 15);      // 0..63
    const int kq = (lane >> 4) * 8;
    const float* wrow = (nl < 32)
        ? (W_rec  + (size_t)(32 * p + nl) * LTC_H)
        : (W_gate + (size_t)(32 * p + nl - 32) * (LTC_D + LTC_H) + LTC_D);
    f16x8 Wf[16];
    #pragma unroll
    for (int ks = 0; ks < 16; ++ks) Wf[ks] = cvt8(wrow + ks * 32 + kq);

    for (int i = tid; i < 16 * 260; i += 256) (&hTu[0][0])[i] = 0;  // h0 = 0
    __syncthreads();

    // ---- update-thread setup (wave 0 only: 4 b x 16 pairs = 64 threads)
    const int ub = tid >> 4;            // local batch (tid<64)
    const int jp = tid & 15;
    const int j0 = 32 * p + 2 * jp;
    const int gb = g * NBG + ub;        // global batch
    float h0 = 0.f, h1 = 0.f, stau0 = 0.f, stau1 = 0.f;
    size_t dwofs = 0;
    if (tid < 64) {
        stau0 = (1.f / 6.f) * __expf(-log_tau[j0]);
        stau1 = (1.f / 6.f) * __expf(-log_tau[j0 + 1]);
        dwofs = (size_t)gb * LTC_L * 256 + 16 * p + jp;
    }

    const _Float16* hrow = (const _Float16*)&hTu[lane & 15][0];
    u32 kp1 = 0;
    int budget = 1 << 22;               // global failing-poll budget (no hangs)

    // prime l=0 inputs
    u32 dw = 0, gw = 0;
    if (tid < 64) { dw = drive[dwofs]; gw = gatex[dwofs]; }

    for (int l = 0; l < LTC_L; ++l) {
        const float d0 = unplo(dw), d1 = unphi(dw);
        const float gx0 = unplo(gw), gx1 = unphi(gw);
        // prefetch next step's inputs (overlaps with 6 sub-steps of work)
        u32 dn = 0, gn = 0;
        if (tid < 64 && l + 1 < LTC_L) {
            dn = drive[dwofs + (size_t)(l + 1) * 256];
            gn = gatex[dwofs + (size_t)(l + 1) * 256];
        }
        #pragma unroll 1
        for (int s = 0; s < 6; ++s) {
            // ---- matvec: red[n][m] = sum_k h[m,k] * Wrow(n)[k] (2 acc chains)
            f32x4 acc0 = (f32x4){0.f, 0.f, 0.f, 0.f}, acc1 = acc0;
            #pragma unroll
            for (int ks = 0; ks < 16; ks += 2) {
                const f16x8 a0 = *(const f16x8*)(hrow + ks * 32 + kq);
                const f16x8 a1 = *(const f16x8*)(hrow + (ks + 1) * 32 + kq);
                acc0 = __builtin_amdgcn_mfma_f32_16x16x32_f16(a0, Wf[ks],     acc0, 0, 0, 0);
                acc1 = __builtin_amdgcn_mfma_f32_16x16x32_f16(a1, Wf[ks + 1], acc1, 0, 0, 0);
            }
            {
                const int n  = wv * 16 + (lane & 15);
                const int rb = (lane >> 4) * 4;
                #pragma unroll
                for (int r = 0; r < 4; ++r) red[n][rb + r] = acc0[r] + acc1[r];
            }
            __syncthreads();
            ++kp1;
            const size_t pbase = (size_t)((kp1 & 1u) * NG + g) * (NBG * 256);
            // ---- update + single LLC publish (fire-and-forget) ----
            if (tid < 64) {
                const float rec0 = red[2 * jp][ub],     gh0 = red[32 + 2 * jp][ub];
                const float rec1 = red[2 * jp + 1][ub], gh1 = red[32 + 2 * jp + 1][ub];
                h0 += stau0 * (sigm(gx0 + gh0) * tanh_f(d0 + rec0) - h0);
                h1 += stau1 * (sigm(gx1 + gh1) * tanh_f(d1 + rec1) - h1);
                const u64 v = ((u64)kp1 << 32) | (u64)packh(h0, h1);
                __hip_atomic_store(hbuf + pbase + (size_t)ub * 256 + 16 * p + jp,
                                   v, __ATOMIC_RELAXED, __HIP_MEMORY_SCOPE_AGENT);
            }
            // ---- gather: column tid across 4 batch rows, batched LLC sweep --
            {
                const u64* sb = hbuf + pbase + tid;
                u64 a0, a1, a2, a3;
                bool ok;
                do {
                    a0 = __hip_atomic_load(sb,       __ATOMIC_RELAXED,
                                           __HIP_MEMORY_SCOPE_AGENT);
                    a1 = __hip_atomic_load(sb + 256, __ATOMIC_RELAXED,
                                           __HIP_MEMORY_SCOPE_AGENT);
                    a2 = __hip_atomic_load(sb + 512, __ATOMIC_RELAXED,
                                           __HIP_MEMORY_SCOPE_AGENT);
                    a3 = __hip_atomic_load(sb + 768, __ATOMIC_RELAXED,
                                           __HIP_MEMORY_SCOPE_AGENT);
                    ok = stamp4(a0, a1, a2, a3, kp1);
                } while (!ok && --budget > 0);
                hTu[0][tid] = (u32)a0; hTu[1][tid] = (u32)a1;
                hTu[2][tid] = (u32)a2; hTu[3][tid] = (u32)a3;
            }
            __syncthreads();
        }
        if (tid < 64) drive[dwofs + (size_t)l * 256] = packh(h0, h1);  // fwd
        dw = dn; gw = gn;
    }
    if (tid < 64) {
        hlast[(size_t)gb * LTC_H + j0]     = h0;
        hlast[(size_t)gb * LTC_H + j0 + 1] = h1;
    }
}

// ---------------------------------------------------------------------------
extern "C" void kernel_launch(void* const* d_in, const int* in_sizes, int n_in,
                              void* d_out, int out_size, void* d_ws, size_t ws_size,
                              hipStream_t stream)
{
    const float* x       = (const float*)d_in[0];
    const float* log_tau = (const float*)d_in[1];
    const float* W_in    = (const float*)d_in[2];
    const float* b_in    = (const float*)d_in[3];
    const float* W_rec   = (const float*)d_in[4];
    const float* W_gate  = (const float*)d_in[5];
    const float* b_gate  = (const float*)d_in[6];
    const float* W_out   = (const float*)d_in[7];
    const float* b_out   = (const float*)d_in[8];

    float* out   = (float*)d_out;                       // (32,1024,512) fp32
    float* hlast = out + (size_t)LTC_B * LTC_L * LTC_H; // (32,512) fp32

    u32* ws    = (u32*)d_ws;                   // 64 MB + 128 KB used
    u32* drive = ws;                           // 8388608 u32 (f16 pairs)
    u32* gatex = ws + 8388608;                 // 8388608 u32
    u64* hbuf  = (u64*)(ws + 16777216);        // 16384 u64 stamped pairs

    const int blocks = (LTC_B * LTC_L / 64) * (LTC_H / 64) / 4;   // 1024

    gemm_a32_c16<<<blocks, 256, 0, stream>>>(x, W_in, LTC_D, b_in, (u16*)drive);
    gemm_a32_c16<<<blocks, 256, 0, stream>>>(x, W_gate, LTC_D + LTC_H, b_gate, (u16*)gatex);
    ltc_scan<<<NG * NP, 256, 0, stream>>>(drive, gatex, W_rec, W_gate, log_tau,
                                          hbuf, hlast);
    gemm_a16_c32<<<blocks, 256, 0, stream>>>((const u16*)drive, W_out, b_out, out);
}